// Round 1
// baseline (777.204 us; speedup 1.0000x reference)
//
#include <hip/hip_runtime.h>

// out[i] = |s| * x[i]  — elementwise scale, memory-bound.
// x: 1,000,000 x 128 fp32 (128M elems, 512 MB). float4 vectorized, coalesced.

__global__ void spherical_scale_v4(const float4* __restrict__ x4,
                                   const float* __restrict__ s,
                                   float4* __restrict__ out4,
                                   long long n4) {
    const float a = fabsf(s[0]);
    long long i = (long long)blockIdx.x * blockDim.x + threadIdx.x;
    if (i < n4) {
        float4 v = x4[i];
        v.x *= a; v.y *= a; v.z *= a; v.w *= a;
        out4[i] = v;
    }
}

__global__ void spherical_scale_tail(const float* __restrict__ x,
                                     const float* __restrict__ s,
                                     float* __restrict__ out,
                                     long long start, long long n) {
    const float a = fabsf(s[0]);
    long long i = start + (long long)blockIdx.x * blockDim.x + threadIdx.x;
    if (i < n) out[i] = a * x[i];
}

extern "C" void kernel_launch(void* const* d_in, const int* in_sizes, int n_in,
                              void* d_out, int out_size, void* d_ws, size_t ws_size,
                              hipStream_t stream) {
    const float* x = (const float*)d_in[0];
    const float* s = (const float*)d_in[1];
    float* out = (float*)d_out;

    const long long n = (long long)in_sizes[0];   // 128,000,000
    const long long n4 = n >> 2;                  // float4 count
    const long long tail_start = n4 << 2;

    const int block = 256;
    if (n4 > 0) {
        long long grid = (n4 + block - 1) / block;
        spherical_scale_v4<<<(unsigned)grid, block, 0, stream>>>(
            (const float4*)x, s, (float4*)out, n4);
    }
    if (tail_start < n) {
        long long rem = n - tail_start;
        long long grid = (rem + block - 1) / block;
        spherical_scale_tail<<<(unsigned)grid, block, 0, stream>>>(
            x, s, out, tail_start, n);
    }
}